// Round 6
// baseline (561.677 us; speedup 1.0000x reference)
//
#include <hip/hip_runtime.h>
#include <stdint.h>

typedef float  floatx4 __attribute__((ext_vector_type(4)));
typedef int    intx4   __attribute__((ext_vector_type(4)));
typedef int    intx8   __attribute__((ext_vector_type(8)));   // 32 fp8 bytes

#define AS1 __attribute__((address_space(1)))
#define AS3 __attribute__((address_space(3)))

// ---------------------------------------------------------------------------
// helpers
// ---------------------------------------------------------------------------
// Round v (pre-clamped to [-448,448]) to the e4m3fn grid, RNE. Exact.
__device__ __forceinline__ float quant_e4m3_value(float v) {
  float av = fabsf(v);
  float step, rstep;
  if (av < 0.015625f) {            // below 2^-6: e4m3 subnormal region
    step  = 0.001953125f;          // 2^-9
    rstep = 512.0f;
  } else {
    uint32_t e = __float_as_uint(av) >> 23;            // biased exponent
    step  = __uint_as_float((e - 3u) << 23);           // 2^(E-3)
    rstep = __uint_as_float((257u - e) << 23);         // 2^(3-E)
  }
  return rintf(v * rstep) * step;
}

// Encode an f32 value EXACTLY on the e4m3fn grid into its byte (pure bit math).
__device__ __forceinline__ uint32_t enc_e4m3(float v) {
  uint32_t u = __float_as_uint(v);
  uint32_t s = (u >> 24) & 0x80u;
  float av = fabsf(v);
  uint32_t b;
  if (av < 0.015625f) {                       // subnormal: m = av*2^9 (0..7)
    b = s | (uint32_t)(av * 512.0f);
  } else {
    uint32_t e = ((u >> 23) & 0xffu) - 120u;  // e4m3 exponent field 1..15
    uint32_t m = (u >> 20) & 7u;
    b = s | (e << 3) | m;
  }
  return b;
}

// ---------------------------------------------------------------------------
// Kernel 1: quantize x (f32): clip(x/s, +-448) -> e4m3 RNE -> raw byte.
// Dense float4 in (16B/thread), uint32 out (4B/thread) — r1 layout (fastest).
// ---------------------------------------------------------------------------
__global__ __launch_bounds__(256) void quantize_x_kernel(
    const float4* __restrict__ x, const float* __restrict__ s_ptr,
    uint32_t* __restrict__ q, int n4) {
  int i = blockIdx.x * 256 + threadIdx.x;
  if (i >= n4) return;
  const float s = s_ptr[0];
  float4 v = x[i];
  float a0 = quant_e4m3_value(fminf(fmaxf(v.x / s, -448.0f), 448.0f));
  float a1 = quant_e4m3_value(fminf(fmaxf(v.y / s, -448.0f), 448.0f));
  float a2 = quant_e4m3_value(fminf(fmaxf(v.z / s, -448.0f), 448.0f));
  float a3 = quant_e4m3_value(fminf(fmaxf(v.w / s, -448.0f), 448.0f));
  q[i] = enc_e4m3(a0) | (enc_e4m3(a1) << 8) | (enc_e4m3(a2) << 16) |
         (enc_e4m3(a3) << 24);
}

// ---------------------------------------------------------------------------
// Kernel 2: weights -> raw e4m3 bytes [N][K], per-block mode detection
// (first 512B of qw, L2-hot, uniform branch). r1 layout (4 elems/thread).
//   mode 2: f32 holding e4m3 values; mode 1: bf16; mode 0: raw fp8 bytes.
// ---------------------------------------------------------------------------
__global__ __launch_bounds__(256) void prep_w_kernel(
    const uint8_t* __restrict__ qw, uint32_t* __restrict__ w8, int n4) {
  const uint32_t* q32 = (const uint32_t*)qw;
  int lane = threadIdx.x & 63;
  uint32_t w0 = q32[lane], w1 = q32[lane + 64];
  bool fa = ((w0 & 0xFFFFFu) == 0u) && ((w1 & 0xFFFFFu) == 0u);
  uint32_t nib = (w0 | (w0 >> 16) | w1 | (w1 >> 16)) & 0xFu;
  unsigned long long ba = __ballot(fa);
  unsigned long long bb = __ballot(nib == 0u);
  int m = (ba == ~0ull) ? 2 : ((bb == ~0ull) ? 1 : 0);

  int i = blockIdx.x * 256 + threadIdx.x;
  if (i >= n4) return;
  uint32_t o;
  if (m == 1) {                       // bf16 storage: <<16 decode (exact), encode
    ushort4 u = ((const ushort4*)qw)[i];
    o = enc_e4m3(__uint_as_float((uint32_t)u.x << 16)) |
        (enc_e4m3(__uint_as_float((uint32_t)u.y << 16)) << 8) |
        (enc_e4m3(__uint_as_float((uint32_t)u.z << 16)) << 16) |
        (enc_e4m3(__uint_as_float((uint32_t)u.w << 16)) << 24);
  } else if (m == 2) {                // f32 storage
    float4 v = ((const float4*)qw)[i];
    o = enc_e4m3(v.x) | (enc_e4m3(v.y) << 8) | (enc_e4m3(v.z) << 16) |
        (enc_e4m3(v.w) << 24);
  } else {                            // raw fp8 bytes: straight copy
    o = ((const uint32_t*)qw)[i];
  }
  w8[i] = o;
}

// ---------------------------------------------------------------------------
// Kernel 3: MX-scaled fp8 GEMM — A in LDS (dbuf 64 KiB), B direct from
// global (L2) into registers. Rationale: LDS pipe (per-CU, shared) was the
// bottleneck at 3700 cy/tile vs matrix 2212; removing B's LDS reads+writes
// drops LDS demand below the matrix pipe -> MFMA-bound.
//   BM=BN=256, BK=128 bytes. 512 thr = 8 waves (2M x 4N); per-wave 128x64 =
//   8x4 frags of mfma_scale_f32_16x16x128_f8f6f4 (e8m0 scale 127 = 1.0).
//   Per tile, ONE barrier: {stage A(t+1) 4x gload_lds -> buf^1 ; load
//   B(t+1) 8x dwordx4 -> regs (auto-vmcnt by compiler: register deps) ;
//   read af + 32 MFMA ; vmcnt(4) [A(t+1) drained, B(t+1) in flight] ;
//   barrier}. Never vmcnt(0) in steady state. B regs double-buffer via
//   2x-unrolled loop with NAMED sets bfA/bfB (no runtime indexing).
//   B frag layout (verified r1): lane holds row wn+j*16+(lane&15), k-bytes
//   [quad*32, quad*32+32) — contiguous 32B -> two dwordx4, full 64B lines.
//   A keeps the verified chunk-XOR swizzle; T1 XCD swizzle; T5 setprio.
// ---------------------------------------------------------------------------
__global__ __launch_bounds__(512, 2) void gemm_fp8_kernel(
    const uint8_t* __restrict__ A, const uint8_t* __restrict__ B,
    const float* __restrict__ wscale, const float* __restrict__ iscale,
    const float* __restrict__ bias, float* __restrict__ out,
    int M, int N, int K) {
  __shared__ uint8_t lds[65536];     // A double buffer: 2 x 32 KiB

  const int tid  = threadIdx.x;
  const int lane = tid & 63;
  const int wave = tid >> 6;

  // T1: XCD swizzle (nwg = 512, % 8 == 0 -> bijective)
  const int nbx = gridDim.x;                 // N/256 = 8
  const int nwg = nbx * gridDim.y;           // 512
  int flat = blockIdx.y * nbx + blockIdx.x;
  flat = (flat & 7) * (nwg >> 3) + (flat >> 3);
  const int bm = flat / nbx;
  const int bn = flat - bm * nbx;

  const int wm = (wave >> 2) * 128;          // 0 / 128
  const int wn = (wave & 3) * 64;            // 0..192
  const int r15 = lane & 15, quad = lane >> 4, k8 = r15 & 7;
  const int posL = ((2 * quad)     ^ k8) << 4;   // swizzled A chunk offsets
  const int posH = ((2 * quad + 1) ^ k8) << 4;

  // A staging: slot s = tid + j*512: local row rl = s>>3 (0..127 per half),
  // LDS chunkpos p = s&7, global chunk = p ^ (rl&7) (involution).
  const uint8_t* aS[2]; uint32_t dOf[2];
#pragma unroll
  for (int j = 0; j < 2; ++j) {
    const int s = tid + j * 512, rl = s >> 3, p = s & 7;
    aS[j] = A + (size_t)(bm * 256 + rl) * K + ((p ^ (rl & 7)) << 4);
    dOf[j] = (uint32_t)s << 4;
  }
  const size_t hK = (size_t)128 * K;         // advance 128 rows

  // B fragment pointers (global, no swizzle)
  const uint8_t* bptr[4];
#pragma unroll
  for (int j = 0; j < 4; ++j)
    bptr[j] = B + (size_t)(bn * 256 + wn + j * 16 + r15) * K + quad * 32;

#define STG_A(j, h, kb, bf_)                                                   \
  __builtin_amdgcn_global_load_lds(                                            \
      (const AS1 void*)(aS[j] + (h) * hK + (kb)),                              \
      (AS3 void*)(&lds[(bf_) * 32768u + (h) * 16384u + dOf[j]]), 16, 0, 0)

  floatx4 acc[8][4];
#pragma unroll
  for (int i = 0; i < 8; ++i)
#pragma unroll
    for (int j = 0; j < 4; ++j) acc[i][j] = (floatx4){0.f, 0.f, 0.f, 0.f};

  intx8 bfA[4], bfB[4];
  const int T = K >> 7;                      // 128-byte K-tiles (T even: K%256==0)

  // ----- prologue: A(0) -> buf0, B(0) -> bfA -----
  STG_A(0, 0, 0, 0); STG_A(1, 0, 0, 0); STG_A(0, 1, 0, 0); STG_A(1, 1, 0, 0);
#pragma unroll
  for (int j = 0; j < 4; ++j) {
    intx4 lo = *(const intx4*)(bptr[j]);
    intx4 hi = *(const intx4*)(bptr[j] + 16);
    bfA[j] = __builtin_shufflevector(lo, hi, 0, 1, 2, 3, 4, 5, 6, 7);
  }
  asm volatile("s_waitcnt vmcnt(0)" ::: "memory");   // prologue edge only
  __builtin_amdgcn_sched_barrier(0);
  __builtin_amdgcn_s_barrier();

  // ----- main loop: 2x unrolled for named B double-buffer -----
#define TILE(t_, USE, LOAD)                                                    \
  do {                                                                         \
    const int cur_ = (t_) & 1;                                                 \
    const uint8_t* LA = &lds[cur_ * 32768u] + (wm + r15) * 128;                \
    if ((t_) + 1 < T) {                                                        \
      const int kb1 = ((t_) + 1) << 7;                                         \
      STG_A(0, 0, kb1, cur_ ^ 1); STG_A(1, 0, kb1, cur_ ^ 1);                  \
      STG_A(0, 1, kb1, cur_ ^ 1); STG_A(1, 1, kb1, cur_ ^ 1);                  \
      __builtin_amdgcn_sched_barrier(0); /* pin A-issue before B-issue */      \
      _Pragma("unroll")                                                        \
      for (int j = 0; j < 4; ++j) {                                            \
        intx4 lo = *(const intx4*)(bptr[j] + kb1);                             \
        intx4 hi = *(const intx4*)(bptr[j] + kb1 + 16);                        \
        LOAD[j] = __builtin_shufflevector(lo, hi, 0, 1, 2, 3, 4, 5, 6, 7);     \
      }                                                                        \
      __builtin_amdgcn_sched_barrier(0);                                       \
    }                                                                          \
    intx8 af[4];                                                               \
    _Pragma("unroll")                                                          \
    for (int i = 0; i < 4; ++i) {                                              \
      intx4 lo = *(const intx4*)(LA + i * 2048 + posL);                        \
      intx4 hi = *(const intx4*)(LA + i * 2048 + posH);                        \
      af[i] = __builtin_shufflevector(lo, hi, 0, 1, 2, 3, 4, 5, 6, 7);         \
    }                                                                          \
    __builtin_amdgcn_s_setprio(1);                                             \
    _Pragma("unroll")                                                          \
    for (int i = 0; i < 4; ++i)                                                \
      _Pragma("unroll")                                                        \
      for (int j = 0; j < 4; ++j)                                              \
        acc[i][j] = __builtin_amdgcn_mfma_scale_f32_16x16x128_f8f6f4(          \
            af[i], USE[j], acc[i][j], 0, 0, 0, 127, 0, 127);                   \
    __builtin_amdgcn_s_setprio(0);                                             \
    _Pragma("unroll")                                                          \
    for (int i = 0; i < 4; ++i) {                                              \
      intx4 lo = *(const intx4*)(LA + 8192 + i * 2048 + posL);                 \
      intx4 hi = *(const intx4*)(LA + 8192 + i * 2048 + posH);                 \
      af[i] = __builtin_shufflevector(lo, hi, 0, 1, 2, 3, 4, 5, 6, 7);         \
    }                                                                          \
    __builtin_amdgcn_s_setprio(1);                                             \
    _Pragma("unroll")                                                          \
    for (int i = 0; i < 4; ++i)                                                \
      _Pragma("unroll")                                                        \
      for (int j = 0; j < 4; ++j)                                              \
        acc[4 + i][j] = __builtin_amdgcn_mfma_scale_f32_16x16x128_f8f6f4(      \
            af[i], USE[j], acc[4 + i][j], 0, 0, 0, 127, 0, 127);               \
    __builtin_amdgcn_s_setprio(0);                                             \
    if ((t_) + 1 < T) {                                                        \
      /* counted drain: A(t+1) landed (plus <=4 old B); B(t+1) stays out */    \
      asm volatile("s_waitcnt vmcnt(4)" ::: "memory");                         \
      __builtin_amdgcn_sched_barrier(0);                                       \
      __builtin_amdgcn_s_barrier();                                            \
    }                                                                          \
  } while (0)

  for (int t = 0; t < T; t += 2) {
    TILE(t,     bfA, bfB);
    TILE(t + 1, bfB, bfA);
  }
#undef TILE
#undef STG_A

  // epilogue: C/D layout col=lane&15, row=quad*4+reg (verified r1/r3/r4/r5)
  const float sc = wscale[0] * iscale[0];
  const int rq = quad * 4;
#pragma unroll
  for (int jj = 0; jj < 4; ++jj) {
    const int col = bn * 256 + wn + jj * 16 + r15;
    const float bv = bias[col];
#pragma unroll
    for (int mi = 0; mi < 8; ++mi) {
      const int row = bm * 256 + wm + (mi >> 2) * 64 + (mi & 3) * 16 + rq;
      float* o = out + (size_t)row * N + col;
#pragma unroll
      for (int r = 0; r < 4; ++r)
        o[(size_t)r * N] = acc[mi][jj][r] * sc + bv;
    }
  }
}

// ---------------------------------------------------------------------------
extern "C" void kernel_launch(void* const* d_in, const int* in_sizes, int n_in,
                              void* d_out, int out_size, void* d_ws,
                              size_t ws_size, hipStream_t stream) {
  const float*   x      = (const float*)d_in[0];   // f32 [M,K]
  const uint8_t* qw     = (const uint8_t*)d_in[1]; // detected per-call [N,K]
  const float*   wscale = (const float*)d_in[2];   // f32 scalar
  const float*   iscale = (const float*)d_in[3];   // f32 scalar
  const float*   bias   = (const float*)d_in[4];   // f32 [N]
  float*         out    = (float*)d_out;

  const int N = in_sizes[4];          // 2048
  const int K = in_sizes[1] / N;      // 2048
  const int M = in_sizes[0] / K;      // 16384

  // ws layout: [0, M*K) qx fp8 ; [+, N*K) w8 fp8
  uint8_t* qx = (uint8_t*)d_ws;
  uint8_t* w8 = qx + (size_t)M * K;

  const int nx4 = in_sizes[0] / 4;
  quantize_x_kernel<<<(nx4 + 255) / 256, 256, 0, stream>>>(
      (const float4*)x, iscale, (uint32_t*)qx, nx4);

  const int nw4 = in_sizes[1] / 4;
  prep_w_kernel<<<(nw4 + 255) / 256, 256, 0, stream>>>(qw, (uint32_t*)w8, nw4);

  dim3 grid(N / 256, M / 256);
  gemm_fp8_kernel<<<grid, 512, 0, stream>>>(qx, w8, wscale, iscale, bias,
                                            out, M, N, K);
}

// Round 7
// 349.955 us; speedup vs baseline: 1.6050x; 1.6050x over previous
//
#include <hip/hip_runtime.h>
#include <stdint.h>

typedef float  floatx4 __attribute__((ext_vector_type(4)));
typedef int    intx4   __attribute__((ext_vector_type(4)));
typedef int    intx8   __attribute__((ext_vector_type(8)));   // 32 fp8 bytes

#define AS1 __attribute__((address_space(1)))
#define AS3 __attribute__((address_space(3)))

// ---------------------------------------------------------------------------
// helpers
// ---------------------------------------------------------------------------
// Round v (pre-clamped to [-448,448]) to the e4m3fn grid, RNE. Exact.
__device__ __forceinline__ float quant_e4m3_value(float v) {
  float av = fabsf(v);
  float step, rstep;
  if (av < 0.015625f) {            // below 2^-6: e4m3 subnormal region
    step  = 0.001953125f;          // 2^-9
    rstep = 512.0f;
  } else {
    uint32_t e = __float_as_uint(av) >> 23;            // biased exponent
    step  = __uint_as_float((e - 3u) << 23);           // 2^(E-3)
    rstep = __uint_as_float((257u - e) << 23);         // 2^(3-E)
  }
  return rintf(v * rstep) * step;
}

// Encode an f32 value EXACTLY on the e4m3fn grid into its byte (pure bit math).
__device__ __forceinline__ uint32_t enc_e4m3(float v) {
  uint32_t u = __float_as_uint(v);
  uint32_t s = (u >> 24) & 0x80u;
  float av = fabsf(v);
  uint32_t b;
  if (av < 0.015625f) {                       // subnormal: m = av*2^9 (0..7)
    b = s | (uint32_t)(av * 512.0f);
  } else {
    uint32_t e = ((u >> 23) & 0xffu) - 120u;  // e4m3 exponent field 1..15
    uint32_t m = (u >> 20) & 7u;
    b = s | (e << 3) | m;
  }
  return b;
}

// ---------------------------------------------------------------------------
// Kernel 1: quantize x (f32): clip(x/s, +-448) -> e4m3 RNE -> raw byte.
// Dense float4 in (16B/thread), uint32 out (4B/thread).
// ---------------------------------------------------------------------------
__global__ __launch_bounds__(256) void quantize_x_kernel(
    const float4* __restrict__ x, const float* __restrict__ s_ptr,
    uint32_t* __restrict__ q, int n4) {
  int i = blockIdx.x * 256 + threadIdx.x;
  if (i >= n4) return;
  const float s = s_ptr[0];
  float4 v = x[i];
  float a0 = quant_e4m3_value(fminf(fmaxf(v.x / s, -448.0f), 448.0f));
  float a1 = quant_e4m3_value(fminf(fmaxf(v.y / s, -448.0f), 448.0f));
  float a2 = quant_e4m3_value(fminf(fmaxf(v.z / s, -448.0f), 448.0f));
  float a3 = quant_e4m3_value(fminf(fmaxf(v.w / s, -448.0f), 448.0f));
  q[i] = enc_e4m3(a0) | (enc_e4m3(a1) << 8) | (enc_e4m3(a2) << 16) |
         (enc_e4m3(a3) << 24);
}

// ---------------------------------------------------------------------------
// Kernel 2: weights -> raw e4m3 bytes [N][K], per-block mode detection
// (first 512B of qw, L2-hot, uniform branch).
//   mode 2: f32 holding e4m3 values; mode 1: bf16; mode 0: raw fp8 bytes.
// ---------------------------------------------------------------------------
__global__ __launch_bounds__(256) void prep_w_kernel(
    const uint8_t* __restrict__ qw, uint32_t* __restrict__ w8, int n4) {
  const uint32_t* q32 = (const uint32_t*)qw;
  int lane = threadIdx.x & 63;
  uint32_t w0 = q32[lane], w1 = q32[lane + 64];
  bool fa = ((w0 & 0xFFFFFu) == 0u) && ((w1 & 0xFFFFFu) == 0u);
  uint32_t nib = (w0 | (w0 >> 16) | w1 | (w1 >> 16)) & 0xFu;
  unsigned long long ba = __ballot(fa);
  unsigned long long bb = __ballot(nib == 0u);
  int m = (ba == ~0ull) ? 2 : ((bb == ~0ull) ? 1 : 0);

  int i = blockIdx.x * 256 + threadIdx.x;
  if (i >= n4) return;
  uint32_t o;
  if (m == 1) {                       // bf16 storage: <<16 decode (exact), encode
    ushort4 u = ((const ushort4*)qw)[i];
    o = enc_e4m3(__uint_as_float((uint32_t)u.x << 16)) |
        (enc_e4m3(__uint_as_float((uint32_t)u.y << 16)) << 8) |
        (enc_e4m3(__uint_as_float((uint32_t)u.z << 16)) << 16) |
        (enc_e4m3(__uint_as_float((uint32_t)u.w << 16)) << 24);
  } else if (m == 2) {                // f32 storage
    float4 v = ((const float4*)qw)[i];
    o = enc_e4m3(v.x) | (enc_e4m3(v.y) << 8) | (enc_e4m3(v.z) << 16) |
        (enc_e4m3(v.w) << 24);
  } else {                            // raw fp8 bytes: straight copy
    o = ((const uint32_t*)qw)[i];
  }
  w8[i] = o;
}

// ---------------------------------------------------------------------------
// Kernel 3: MX-scaled fp8 GEMM — A in LDS (dbuf 2x32K), B direct from L2
// into transient registers (NO B double-buffer: r6's +64-VGPR dbuf spilled
// to scratch, WRITE_SIZE 842MB). B panel = 4MB, L2-resident; per-half frag
// reload is L1-hot. LDS demand/tile drops ~3780cy -> ~1750cy (< 2212cy
// matrix pipe) => MFMA-bound for the first time.
//   BM=BN=256, BK=128 bytes. 512 thr = 8 waves (2M x 4N); per-wave 128x64 =
//   8x4 frags of mfma_scale_f32_16x16x128_f8f6f4 (e8m0 scale 127 = 1.0).
//   Per tile, ONE barrier:
//     issue 8 B-half0 reg loads            (oldest)
//     [sched_barrier] issue 4 A(t+1) gload_lds -> buf^1
//     [sched_barrier] af0 ds_reads ; compiler B-wait = vmcnt(4) -> A stays
//     16 MFMA (setprio)
//     issue 8 B-half1 loads ; af1 ds_reads ; (vmcnt(0) here is free: A
//     issued ~1tile=~2000cy ago > 900cy HBM)
//     16 MFMA (setprio)
//     vmcnt(0) [A(t+1) landed] ; barrier.
//   A keeps the verified chunk-XOR swizzle (linear gload_lds dest +
//   pre-swizzled global src + swizzled ds_read). T1 XCD swizzle, T5 setprio.
//   Peak VGPR ~100 (acc 128 AGPR + bf32 + af32 transient) -> no spill.
// ---------------------------------------------------------------------------
__global__ __launch_bounds__(512, 2) void gemm_fp8_kernel(
    const uint8_t* __restrict__ A, const uint8_t* __restrict__ B,
    const float* __restrict__ wscale, const float* __restrict__ iscale,
    const float* __restrict__ bias, float* __restrict__ out,
    int M, int N, int K) {
  __shared__ uint8_t lds[65536];     // A double buffer: 2 x 32 KiB

  const int tid  = threadIdx.x;
  const int lane = tid & 63;
  const int wave = tid >> 6;

  // T1: XCD swizzle (nwg = 512, % 8 == 0 -> bijective)
  const int nbx = gridDim.x;                 // N/256 = 8
  const int nwg = nbx * gridDim.y;           // 512
  int flat = blockIdx.y * nbx + blockIdx.x;
  flat = (flat & 7) * (nwg >> 3) + (flat >> 3);
  const int bm = flat / nbx;
  const int bn = flat - bm * nbx;

  const int wm = (wave >> 2) * 128;          // 0 / 128
  const int wn = (wave & 3) * 64;            // 0..192
  const int r15 = lane & 15, quad = lane >> 4, k8 = r15 & 7;
  const int posL = ((2 * quad)     ^ k8) << 4;   // swizzled A chunk offsets
  const int posH = ((2 * quad + 1) ^ k8) << 4;

  // A staging: slot s = tid + j*512: local row rl = s>>3 (0..127 per half),
  // LDS chunkpos p = s&7, global chunk = p ^ (rl&7) (involution).
  const uint8_t* aS[2]; uint32_t dOf[2];
#pragma unroll
  for (int j = 0; j < 2; ++j) {
    const int s = tid + j * 512, rl = s >> 3, p = s & 7;
    aS[j] = A + (size_t)(bm * 256 + rl) * K + ((p ^ (rl & 7)) << 4);
    dOf[j] = (uint32_t)s << 4;
  }
  const size_t hK = (size_t)128 * K;         // advance 128 rows

  // B fragment pointers (global; rows wn+j*16+r15, k-bytes [quad*32,+32))
  const uint8_t* bptr[4];
#pragma unroll
  for (int j = 0; j < 4; ++j)
    bptr[j] = B + (size_t)(bn * 256 + wn + j * 16 + r15) * K + quad * 32;

#define STG_A(j, h, kb, bf_)                                                   \
  __builtin_amdgcn_global_load_lds(                                            \
      (const AS1 void*)(aS[j] + (h) * hK + (kb)),                              \
      (AS3 void*)(&lds[(bf_) * 32768u + (h) * 16384u + dOf[j]]), 16, 0, 0)

  floatx4 acc[8][4];
#pragma unroll
  for (int i = 0; i < 8; ++i)
#pragma unroll
    for (int j = 0; j < 4; ++j) acc[i][j] = (floatx4){0.f, 0.f, 0.f, 0.f};

  const int T = K >> 7;                      // 128-byte K-tiles

  // ----- prologue: A(0) -> buf0 -----
  STG_A(0, 0, 0, 0); STG_A(1, 0, 0, 0); STG_A(0, 1, 0, 0); STG_A(1, 1, 0, 0);
  asm volatile("s_waitcnt vmcnt(0)" ::: "memory");
  __builtin_amdgcn_sched_barrier(0);
  __builtin_amdgcn_s_barrier();

  for (int t = 0; t < T; ++t) {
    const int cur = t & 1;
    const uint8_t* LA = &lds[cur * 32768u] + (wm + r15) * 128;
    const int kb0 = t << 7;
    intx8 af[4], bf[4];

    // --- B half-0 loads first (oldest in vmcnt order) ---
#pragma unroll
    for (int j = 0; j < 4; ++j) {
      intx4 lo = *(const intx4*)(bptr[j] + kb0);
      intx4 hi = *(const intx4*)(bptr[j] + kb0 + 16);
      bf[j] = __builtin_shufflevector(lo, hi, 0, 1, 2, 3, 4, 5, 6, 7);
    }
    __builtin_amdgcn_sched_barrier(0);

    // --- A(t+1) prefetch (younger than B0 => B0-wait = vmcnt(4)) ---
    if (t + 1 < T) {
      const int kb1 = (t + 1) << 7;
      STG_A(0, 0, kb1, cur ^ 1); STG_A(1, 0, kb1, cur ^ 1);
      STG_A(0, 1, kb1, cur ^ 1); STG_A(1, 1, kb1, cur ^ 1);
    }
    __builtin_amdgcn_sched_barrier(0);

    // ---------- half 0: af m-half0 + 16 MFMA ----------
#pragma unroll
    for (int i = 0; i < 4; ++i) {
      intx4 lo = *(const intx4*)(LA + i * 2048 + posL);
      intx4 hi = *(const intx4*)(LA + i * 2048 + posH);
      af[i] = __builtin_shufflevector(lo, hi, 0, 1, 2, 3, 4, 5, 6, 7);
    }
    __builtin_amdgcn_s_setprio(1);
#pragma unroll
    for (int i = 0; i < 4; ++i)
#pragma unroll
      for (int j = 0; j < 4; ++j)
        acc[i][j] = __builtin_amdgcn_mfma_scale_f32_16x16x128_f8f6f4(
            af[i], bf[j], acc[i][j], 0, 0, 0, 127, 0, 127);
    __builtin_amdgcn_s_setprio(0);

    // ---------- half 1: reload B (L1-hot) + af m-half1 + 16 MFMA ----------
#pragma unroll
    for (int j = 0; j < 4; ++j) {
      intx4 lo = *(const intx4*)(bptr[j] + kb0);
      intx4 hi = *(const intx4*)(bptr[j] + kb0 + 16);
      bf[j] = __builtin_shufflevector(lo, hi, 0, 1, 2, 3, 4, 5, 6, 7);
    }
#pragma unroll
    for (int i = 0; i < 4; ++i) {
      intx4 lo = *(const intx4*)(LA + 8192 + i * 2048 + posL);
      intx4 hi = *(const intx4*)(LA + 8192 + i * 2048 + posH);
      af[i] = __builtin_shufflevector(lo, hi, 0, 1, 2, 3, 4, 5, 6, 7);
    }
    __builtin_amdgcn_s_setprio(1);
#pragma unroll
    for (int i = 0; i < 4; ++i)
#pragma unroll
      for (int j = 0; j < 4; ++j)
        acc[4 + i][j] = __builtin_amdgcn_mfma_scale_f32_16x16x128_f8f6f4(
            af[i], bf[j], acc[4 + i][j], 0, 0, 0, 127, 0, 127);
    __builtin_amdgcn_s_setprio(0);

    // --- dbuf handoff: A(t+1) must land (issued ~1 tile ago => cheap) ---
    if (t + 1 < T) {
      asm volatile("s_waitcnt vmcnt(0)" ::: "memory");
      __builtin_amdgcn_sched_barrier(0);
      __builtin_amdgcn_s_barrier();
    }
  }
#undef STG_A

  // epilogue: C/D layout col=lane&15, row=quad*4+reg (verified r1/r3/r4/r5)
  const float sc = wscale[0] * iscale[0];
  const int rq = quad * 4;
#pragma unroll
  for (int jj = 0; jj < 4; ++jj) {
    const int col = bn * 256 + wn + jj * 16 + r15;
    const float bv = bias[col];
#pragma unroll
    for (int mi = 0; mi < 8; ++mi) {
      const int row = bm * 256 + wm + (mi >> 2) * 64 + (mi & 3) * 16 + rq;
      float* o = out + (size_t)row * N + col;
#pragma unroll
      for (int r = 0; r < 4; ++r)
        o[(size_t)r * N] = acc[mi][jj][r] * sc + bv;
    }
  }
}

// ---------------------------------------------------------------------------
extern "C" void kernel_launch(void* const* d_in, const int* in_sizes, int n_in,
                              void* d_out, int out_size, void* d_ws,
                              size_t ws_size, hipStream_t stream) {
  const float*   x      = (const float*)d_in[0];   // f32 [M,K]
  const uint8_t* qw     = (const uint8_t*)d_in[1]; // detected per-call [N,K]
  const float*   wscale = (const float*)d_in[2];   // f32 scalar
  const float*   iscale = (const float*)d_in[3];   // f32 scalar
  const float*   bias   = (const float*)d_in[4];   // f32 [N]
  float*         out    = (float*)d_out;

  const int N = in_sizes[4];          // 2048
  const int K = in_sizes[1] / N;      // 2048
  const int M = in_sizes[0] / K;      // 16384

  // ws layout: [0, M*K) qx fp8 ; [+, N*K) w8 fp8
  uint8_t* qx = (uint8_t*)d_ws;
  uint8_t* w8 = qx + (size_t)M * K;

  const int nx4 = in_sizes[0] / 4;
  quantize_x_kernel<<<(nx4 + 255) / 256, 256, 0, stream>>>(
      (const float4*)x, iscale, (uint32_t*)qx, nx4);

  const int nw4 = in_sizes[1] / 4;
  prep_w_kernel<<<(nw4 + 255) / 256, 256, 0, stream>>>(qw, (uint32_t*)w8, nw4);

  dim3 grid(N / 256, M / 256);
  gemm_fp8_kernel<<<grid, 512, 0, stream>>>(qx, w8, wscale, iscale, bias,
                                            out, M, N, K);
}